// Round 1
// 59467.535 us; speedup vs baseline: 1.7360x; 1.7360x over previous
//
#include <hip/hip_runtime.h>

// DeepLSTM: B=32, S=512, IN=512, H=1024, 3H=3072, L=4
// out (fp32): cur [32][512][1024] | h_finals [4][32][1024] | c_finals [4][32][1024]
// ws (~192 MiB): Xp fp32 | hbuf_hi | hbuf_lo | bar(flags)
// Precision: split-bf16 (hi+lo) 3-term MFMA everywhere (~2^-16 rel); Xp fp32;
// inter-layer y fp32 staged in d_out's cur region; h carried as (hi,lo) bf16 planes;
// c in fp32 register.
// R1 change: grid barrier rebuilt as distributed per-block flags (relaxed agent
// store + relaxed coalesced polling + single release/acquire fence) replacing the
// 512-way same-line ACQ_REL fetch_add + ACQUIRE spin (which serialized ~30 us/step
// and invalidated L2 per poll). Blocks 512x64 -> 256x128 (2 waves share W slice).
// XCD-grouped unit mapping for Xp/yOut L2 line sharing. Xp loads hoisted over matvec.

typedef unsigned short ushort_t;
typedef __attribute__((ext_vector_type(4))) float f32x4;
typedef __attribute__((ext_vector_type(8))) short s16x8;
typedef __attribute__((ext_vector_type(4))) short s16x4;

__device__ __forceinline__ unsigned short f2bf(float f) {
  union { float f; unsigned u; } v; v.f = f;
  unsigned r = (v.u + 0x7fffu + ((v.u >> 16) & 1u)) >> 16;
  return (unsigned short)r;
}
__device__ __forceinline__ float bf2f(unsigned short h) {
  union { unsigned u; float f; } v; v.u = ((unsigned)h) << 16; return v.f;
}
__device__ __forceinline__ void split2(float x, short& hi, short& lo) {
  unsigned short h = f2bf(x);
  hi = (short)h;
  lo = (short)f2bf(x - bf2f(h));
}

// ---------------- split-bf16 GEMM: C[m][n] = sum_k A[m][k]*Bw[n][k] + bias[n] ----------------
// A: fp32 [M][K]; Bw: fp32 [N][K]; C: fp32 [M][N]. BM=BN=128, BK=32. (unchanged)
#define BM 128
#define BN 128
#define BK 32
__global__ __launch_bounds__(256) void k_gemm_split(
    const float* __restrict__ A, const float* __restrict__ Bw,
    const float* __restrict__ bias, float* __restrict__ C,
    int M, int N, int K) {
  __shared__ short Ah[BM * BK], Al[BM * BK];
  __shared__ short Bh[BN * BK], Bl[BN * BK];
  const int tid = threadIdx.x;
  const int nbm = M / BM;
  const int bm = blockIdx.x % nbm;
  const int bn = blockIdx.x / nbm;
  const int lane = tid & 63;
  const int wave = tid >> 6;
  const int wm = (wave & 1) * 64;
  const int wn = (wave >> 1) * 64;
  const int q = lane >> 4;
  f32x4 acc[4][4] = {};
  const int nk = K / BK;
  for (int kt = 0; kt < nk; ++kt) {
    __syncthreads();
    const int kb = kt * BK;
#pragma unroll
    for (int i = 0; i < 4; ++i) {
      int idx = tid + i * 256;            // 0..1023
      int row = idx >> 3, c4 = (idx & 7) * 4;
      f32x4 ta = *(const f32x4*)(A + (size_t)(bm * BM + row) * K + kb + c4);
      s16x4 h4, l4;
#pragma unroll
      for (int j = 0; j < 4; ++j) { short hh, ll; split2(ta[j], hh, ll); h4[j] = hh; l4[j] = ll; }
      *(s16x4*)&Ah[row * BK + c4] = h4;
      *(s16x4*)&Al[row * BK + c4] = l4;
      f32x4 tb = *(const f32x4*)(Bw + (size_t)(bn * BN + row) * K + kb + c4);
#pragma unroll
      for (int j = 0; j < 4; ++j) { short hh, ll; split2(tb[j], hh, ll); h4[j] = hh; l4[j] = ll; }
      *(s16x4*)&Bh[row * BK + c4] = h4;
      *(s16x4*)&Bl[row * BK + c4] = l4;
    }
    __syncthreads();
    s16x8 ah[4], al[4], bh[4], bl[4];
#pragma unroll
    for (int i = 0; i < 4; ++i) {
      int r = (wm + i * 16 + (lane & 15)) * BK + q * 8;
      ah[i] = *(const s16x8*)&Ah[r];
      al[i] = *(const s16x8*)&Al[r];
      int rb = (wn + i * 16 + (lane & 15)) * BK + q * 8;
      bh[i] = *(const s16x8*)&Bh[rb];
      bl[i] = *(const s16x8*)&Bl[rb];
    }
#pragma unroll
    for (int mi = 0; mi < 4; ++mi)
#pragma unroll
      for (int ni = 0; ni < 4; ++ni) {
        acc[mi][ni] = __builtin_amdgcn_mfma_f32_16x16x32_bf16(ah[mi], bh[ni], acc[mi][ni], 0, 0, 0);
        acc[mi][ni] = __builtin_amdgcn_mfma_f32_16x16x32_bf16(al[mi], bh[ni], acc[mi][ni], 0, 0, 0);
        acc[mi][ni] = __builtin_amdgcn_mfma_f32_16x16x32_bf16(ah[mi], bl[ni], acc[mi][ni], 0, 0, 0);
      }
  }
#pragma unroll
  for (int mi = 0; mi < 4; ++mi)
#pragma unroll
    for (int ni = 0; ni < 4; ++ni) {
      int col = bn * BN + wn + ni * 16 + (lane & 15);
      float bv = bias[col];
#pragma unroll
      for (int r = 0; r < 4; ++r) {
        int row = bm * BM + wm + mi * 16 + q * 4 + r;
        C[(size_t)row * N + col] = acc[mi][ni][r] + bv;
      }
    }
}

// ---------------- persistent recurrent kernel (one layer, 512 steps) ----------------
// 256 blocks x 128 threads (2 waves). Wave g in {0,1}: batch group g*16..g*16+15.
// Block owns 4 hidden units u0..u0+3 (all 3 gates): s = (bid&7)*32 + (bid>>3) so
// consecutive unit-slices land on the same XCD (Xp/yOut 64B-line sharing in L2).
// LDS: split W_hh tile, 12 rows x K=1024, hi+lo = 48KB (shared by both waves) + red 2KB.
__global__ __launch_bounds__(128) void k_recurrent(
    const float* __restrict__ Xp,     // [16384][3072] fp32: x@Wih^T + b (rows m=b*512+t)
    const float* __restrict__ Whh,    // [3072][1024] fp32 (original weights)
    ushort_t* __restrict__ hhi,       // [2][32][1024] bf16 hi plane (pre-zeroed)
    ushort_t* __restrict__ hlo,       // [2][32][1024] bf16 lo plane
    float* __restrict__ yOut,         // [32][512][1024] fp32: layer output (cur region)
    float* __restrict__ hOut,         // [32][1024] f32
    float* __restrict__ cOut,         // [32][1024] f32
    int* __restrict__ bar)            // [256] per-block step flags, zeroed
{
  __shared__ short Wh[128 * 12 * 8];  // [kq][n][8] hi, 24 KB
  __shared__ short Wl[128 * 12 * 8];  // lo, 24 KB
  __shared__ float red[2][16][16];    // [g][batch][n], n: 0-3 i, 4-7 g, 8-11 o
  const int tid = threadIdx.x;
  const int lane = tid & 63;
  const int g = tid >> 6;             // wave = batch group
  const int bid = blockIdx.x;
  const int s = ((bid & 7) << 5) | (bid >> 3);  // XCD-grouped unit slice, bijective on [0,256)
  const int u0 = s * 4;
  const int b0 = g * 16;

  // stage + split W_hh rows for this slice (one-time, both waves cooperate)
  for (int p = tid; p < 1536; p += 128) {
    int n = p >> 7, kq = p & 127;
    int row = (n < 4) ? (u0 + n) : (n < 8) ? (1024 + u0 + (n - 4)) : (2048 + u0 + (n - 8));
    const float* src = Whh + (size_t)row * 1024 + kq * 8;
    f32x4 v0 = *(const f32x4*)src;
    f32x4 v1 = *(const f32x4*)(src + 4);
    s16x4 h4, l4;
#pragma unroll
    for (int j = 0; j < 4; ++j) { short hh, ll; split2(v0[j], hh, ll); h4[j] = hh; l4[j] = ll; }
    *(s16x4*)&Wh[(kq * 12 + n) * 8] = h4;
    *(s16x4*)&Wl[(kq * 12 + n) * 8] = l4;
#pragma unroll
    for (int j = 0; j < 4; ++j) { short hh, ll; split2(v1[j], hh, ll); h4[j] = hh; l4[j] = ll; }
    *(s16x4*)&Wh[(kq * 12 + n) * 8 + 4] = h4;
    *(s16x4*)&Wl[(kq * 12 + n) * 8 + 4] = l4;
  }

  const int m = lane & 15;            // batch-in-group (A row)
  const int q = lane >> 4;            // k quad
  const bool nvalid = m < 12;
  const int eb = (tid >> 2) & 15;     // elementwise batch-in-group
  const int eu = tid & 3;             // elementwise unit
  float c = 0.f;                      // cell state in register across all 512 steps
  __syncthreads();

  for (int t = 0; t < 512; ++t) {
    const int par = t & 1;
    // --- gate-input loads hoisted above matvec: latency hides under MFMA loop ---
    const size_t mrow = (size_t)(b0 + eb) * 512 + t;
    const float xi = Xp[mrow * 3072 + (u0 + eu)];
    const float xg = Xp[mrow * 3072 + 1024 + (u0 + eu)];
    const float xo = Xp[mrow * 3072 + 2048 + (u0 + eu)];

    // --- matvec: D[batch][n] = sum_k h[batch][k] * W[n][k], split-bf16 3-term ---
    const size_t hbase = (size_t)par * 32768 + (size_t)(b0 + m) * 1024 + q * 8;
    f32x4 a0 = {0.f, 0.f, 0.f, 0.f}, a1 = a0, a2 = a0;
#pragma unroll 8
    for (int kc = 0; kc < 32; ++kc) {
      s16x8 ahf = *(const s16x8*)&hhi[hbase + kc * 32];
      s16x8 alf = *(const s16x8*)&hlo[hbase + kc * 32];
      s16x8 bhf = {}, blf = {};
      if (nvalid) {
        bhf = *(const s16x8*)&Wh[(((kc * 4 + q) * 12) + m) * 8];
        blf = *(const s16x8*)&Wl[(((kc * 4 + q) * 12) + m) * 8];
      }
      a0 = __builtin_amdgcn_mfma_f32_16x16x32_bf16(ahf, bhf, a0, 0, 0, 0);
      a1 = __builtin_amdgcn_mfma_f32_16x16x32_bf16(alf, bhf, a1, 0, 0, 0);
      a2 = __builtin_amdgcn_mfma_f32_16x16x32_bf16(ahf, blf, a2, 0, 0, 0);
    }
#pragma unroll
    for (int r = 0; r < 4; ++r)
      red[g][q * 4 + r][m] = a0[r] + a1[r] + a2[r];
    __syncthreads();

    // --- elementwise cell update: one thread per (g,b,u) ---
    {
      float ig = xi + red[g][eb][eu];
      float gg = xg + red[g][eb][4 + eu];
      float og = xo + red[g][eb][8 + eu];
      float si = 1.f / (1.f + expf(-ig));
      float tg = tanhf(gg);
      c += si * tg;
      float so = 1.f / (1.f + expf(-og));
      float h = so * tanhf(c);
      short hh, hl;
      split2(h, hh, hl);
      size_t hw = (size_t)(1 - par) * 32768 + (size_t)(b0 + eb) * 1024 + (u0 + eu);
      hhi[hw] = (ushort_t)hh;
      hlo[hw] = (ushort_t)hl;
      yOut[mrow * 1024 + (u0 + eu)] = h;
      if (t == 511) {
        hOut[(size_t)(b0 + eb) * 1024 + (u0 + eu)] = h;
        cOut[(size_t)(b0 + eb) * 1024 + (u0 + eu)] = c;
      }
    }
    if (t == 511) break;  // no successor step: kernel-end flush publishes outputs

    // ---- distributed-flag grid barrier (no RMW contention, no per-poll inv) ----
    __builtin_amdgcn_fence(__ATOMIC_RELEASE, "agent");  // waitcnt + wbl2: h at LLC
    __syncthreads();
    if (tid == 0)
      __hip_atomic_store(&bar[bid], t + 1, __ATOMIC_RELAXED, __HIP_MEMORY_SCOPE_AGENT);
    const int tgt = t + 1;
    for (;;) {
      int f0 = __hip_atomic_load(&bar[tid], __ATOMIC_RELAXED, __HIP_MEMORY_SCOPE_AGENT);
      int f1 = __hip_atomic_load(&bar[tid + 128], __ATOMIC_RELAXED, __HIP_MEMORY_SCOPE_AGENT);
      if (__syncthreads_and((f0 >= tgt) && (f1 >= tgt))) break;
      __builtin_amdgcn_s_sleep(1);
    }
    __builtin_amdgcn_fence(__ATOMIC_ACQUIRE, "agent"); // inv L2 before reading fresh h
  }
}

// ---------------- host ----------------
extern "C" void kernel_launch(void* const* d_in, const int* in_sizes, int n_in,
                              void* d_out, int out_size, void* d_ws, size_t ws_size,
                              hipStream_t stream) {
  const float* x     = (const float*)d_in[0];
  const float* w_ih0 = (const float*)d_in[1];
  const float* w_hh0 = (const float*)d_in[2];
  const float* b0v   = (const float*)d_in[3];
  const float* w_ihr = (const float*)d_in[4];
  const float* w_hhr = (const float*)d_in[5];
  const float* b_r   = (const float*)d_in[6];
  float* out = (float*)d_out;

  char* ws = (char*)d_ws;
  float*    Xp  = (float*)(ws);                    // 201,326,592 B
  ushort_t* hhi = (ushort_t*)(ws + 201326592);     //     131,072 B
  ushort_t* hlo = (ushort_t*)(ws + 201457664);     //     131,072 B
  int*      bar = (int*)(ws + 201588736);          //       8,192 B (~192.3 MiB total)

  float* yBuf     = out;                 // cur region doubles as inter-layer y staging
  float* hOutBase = out + 16777216;
  float* cOutBase = out + 16777216 + 131072;

  hipMemsetAsync(bar, 0, 8192, stream);

  for (int l = 0; l < 4; ++l) {
    const float* wih  = (l == 0) ? w_ih0 : (w_ihr + (size_t)(l - 1) * 3072 * 1024);
    const float* whh  = (l == 0) ? w_hh0 : (w_hhr + (size_t)(l - 1) * 3072 * 1024);
    const float* bias = (l == 0) ? b0v : (b_r + (size_t)(l - 1) * 3072);
    const int K = (l == 0) ? 512 : 1024;
    const float* Ain = (l == 0) ? x : yBuf;
    dim3 ggrid((16384 / BM) * (3072 / BN));
    k_gemm_split<<<ggrid, 256, 0, stream>>>(Ain, wih, bias, Xp, 16384, 3072, K);
    hipMemsetAsync(hhi, 0, 131072, stream);
    hipMemsetAsync(hlo, 0, 131072, stream);
    float* hO = hOutBase + (size_t)l * 32768;
    float* cO = cOutBase + (size_t)l * 32768;
    int* barL = bar + l * 512;   // 256 flags used per layer; fresh zeroed region
    void* args[] = { (void*)&Xp, (void*)&whh, (void*)&hhi, (void*)&hlo, (void*)&yBuf,
                     (void*)&hO, (void*)&cO, (void*)&barL };
    if (hipLaunchCooperativeKernel((void*)k_recurrent, dim3(256), dim3(128),
                                   args, 0, stream) != hipSuccess) {
      // fallback: plain launch (256 blocks, 50KB LDS, 128 thr -> all co-resident)
      k_recurrent<<<dim3(256), dim3(128), 0, stream>>>(Xp, whh, hhi, hlo, yBuf,
                                                       hO, cO, barL);
    }
  }
}

// Round 2
// 52690.399 us; speedup vs baseline: 1.9592x; 1.1286x over previous
//
#include <hip/hip_runtime.h>

// DeepLSTM: B=32, S=512, IN=512, H=1024, 3H=3072, L=4
// out (fp32): cur [32][512][1024] | h_finals [4][32][1024] | c_finals [4][32][1024]
// ws (~192 MiB): Xp fp32 | hbuf_hi | hbuf_lo | bar(flags+epoch)
// Precision: split-bf16 (hi+lo) 3-term MFMA everywhere (~2^-16 rel); Xp fp32;
// inter-layer y fp32 staged in d_out's cur region; h carried as (hi,lo) bf16 planes;
// c in fp32 register.
// R1: distributed-flag barrier (relaxed stores) replaced 512-way same-line fetch_add.
// R2: kill the poll-storm. R1 had 32K threads polling 16 flag lines with L2-bypassing
// loads -> ~65K serialized LLC requests/round ~= the 26us/step residual + the 2-4x
// dispatch variance. Now: master block (bid 0) alone gathers the 256 flags, then
// broadcasts one epoch word; workers poll epoch with ONE thread each. Poll traffic
// drops ~500x. Fence chain worker-rel -> flag -> master-acqrel -> epoch -> worker-acq
// preserves the h-plane happens-before transitively.

typedef unsigned short ushort_t;
typedef __attribute__((ext_vector_type(4))) float f32x4;
typedef __attribute__((ext_vector_type(8))) short s16x8;
typedef __attribute__((ext_vector_type(4))) short s16x4;

__device__ __forceinline__ unsigned short f2bf(float f) {
  union { float f; unsigned u; } v; v.f = f;
  unsigned r = (v.u + 0x7fffu + ((v.u >> 16) & 1u)) >> 16;
  return (unsigned short)r;
}
__device__ __forceinline__ float bf2f(unsigned short h) {
  union { unsigned u; float f; } v; v.u = ((unsigned)h) << 16; return v.f;
}
__device__ __forceinline__ void split2(float x, short& hi, short& lo) {
  unsigned short h = f2bf(x);
  hi = (short)h;
  lo = (short)f2bf(x - bf2f(h));
}

// ---------------- split-bf16 GEMM: C[m][n] = sum_k A[m][k]*Bw[n][k] + bias[n] ----------------
// A: fp32 [M][K]; Bw: fp32 [N][K]; C: fp32 [M][N]. BM=BN=128, BK=32. (unchanged)
#define BM 128
#define BN 128
#define BK 32
__global__ __launch_bounds__(256) void k_gemm_split(
    const float* __restrict__ A, const float* __restrict__ Bw,
    const float* __restrict__ bias, float* __restrict__ C,
    int M, int N, int K) {
  __shared__ short Ah[BM * BK], Al[BM * BK];
  __shared__ short Bh[BN * BK], Bl[BN * BK];
  const int tid = threadIdx.x;
  const int nbm = M / BM;
  const int bm = blockIdx.x % nbm;
  const int bn = blockIdx.x / nbm;
  const int lane = tid & 63;
  const int wave = tid >> 6;
  const int wm = (wave & 1) * 64;
  const int wn = (wave >> 1) * 64;
  const int q = lane >> 4;
  f32x4 acc[4][4] = {};
  const int nk = K / BK;
  for (int kt = 0; kt < nk; ++kt) {
    __syncthreads();
    const int kb = kt * BK;
#pragma unroll
    for (int i = 0; i < 4; ++i) {
      int idx = tid + i * 256;            // 0..1023
      int row = idx >> 3, c4 = (idx & 7) * 4;
      f32x4 ta = *(const f32x4*)(A + (size_t)(bm * BM + row) * K + kb + c4);
      s16x4 h4, l4;
#pragma unroll
      for (int j = 0; j < 4; ++j) { short hh, ll; split2(ta[j], hh, ll); h4[j] = hh; l4[j] = ll; }
      *(s16x4*)&Ah[row * BK + c4] = h4;
      *(s16x4*)&Al[row * BK + c4] = l4;
      f32x4 tb = *(const f32x4*)(Bw + (size_t)(bn * BN + row) * K + kb + c4);
#pragma unroll
      for (int j = 0; j < 4; ++j) { short hh, ll; split2(tb[j], hh, ll); h4[j] = hh; l4[j] = ll; }
      *(s16x4*)&Bh[row * BK + c4] = h4;
      *(s16x4*)&Bl[row * BK + c4] = l4;
    }
    __syncthreads();
    s16x8 ah[4], al[4], bh[4], bl[4];
#pragma unroll
    for (int i = 0; i < 4; ++i) {
      int r = (wm + i * 16 + (lane & 15)) * BK + q * 8;
      ah[i] = *(const s16x8*)&Ah[r];
      al[i] = *(const s16x8*)&Al[r];
      int rb = (wn + i * 16 + (lane & 15)) * BK + q * 8;
      bh[i] = *(const s16x8*)&Bh[rb];
      bl[i] = *(const s16x8*)&Bl[rb];
    }
#pragma unroll
    for (int mi = 0; mi < 4; ++mi)
#pragma unroll
      for (int ni = 0; ni < 4; ++ni) {
        acc[mi][ni] = __builtin_amdgcn_mfma_f32_16x16x32_bf16(ah[mi], bh[ni], acc[mi][ni], 0, 0, 0);
        acc[mi][ni] = __builtin_amdgcn_mfma_f32_16x16x32_bf16(al[mi], bh[ni], acc[mi][ni], 0, 0, 0);
        acc[mi][ni] = __builtin_amdgcn_mfma_f32_16x16x32_bf16(ah[mi], bl[ni], acc[mi][ni], 0, 0, 0);
      }
  }
#pragma unroll
  for (int mi = 0; mi < 4; ++mi)
#pragma unroll
    for (int ni = 0; ni < 4; ++ni) {
      int col = bn * BN + wn + ni * 16 + (lane & 15);
      float bv = bias[col];
#pragma unroll
      for (int r = 0; r < 4; ++r) {
        int row = bm * BM + wm + mi * 16 + q * 4 + r;
        C[(size_t)row * N + col] = acc[mi][ni][r] + bv;
      }
    }
}

// ---------------- persistent recurrent kernel (one layer, 512 steps) ----------------
// 256 blocks x 128 threads (2 waves). Wave g in {0,1}: batch group g*16..g*16+15.
// Block owns 4 hidden units u0..u0+3 (all 3 gates): s = (bid&7)*32 + (bid>>3) so
// consecutive unit-slices land on the same XCD (Xp/yOut 64B-line sharing in L2).
// LDS: split W_hh tile, 12 rows x K=1024, hi+lo = 48KB (shared by both waves) + red 2KB.
// bar layout (per layer, 512 ints): [0..255] per-block step flags, [256] epoch word.
__global__ __launch_bounds__(128) void k_recurrent(
    const float* __restrict__ Xp,     // [16384][3072] fp32: x@Wih^T + b (rows m=b*512+t)
    const float* __restrict__ Whh,    // [3072][1024] fp32 (original weights)
    ushort_t* __restrict__ hhi,       // [2][32][1024] bf16 hi plane (pre-zeroed)
    ushort_t* __restrict__ hlo,       // [2][32][1024] bf16 lo plane
    float* __restrict__ yOut,         // [32][512][1024] fp32: layer output (cur region)
    float* __restrict__ hOut,         // [32][1024] f32
    float* __restrict__ cOut,         // [32][1024] f32
    int* __restrict__ bar)            // [512] ints: flags[256] + epoch, zeroed
{
  __shared__ short Wh[128 * 12 * 8];  // [kq][n][8] hi, 24 KB
  __shared__ short Wl[128 * 12 * 8];  // lo, 24 KB
  __shared__ float red[2][16][16];    // [g][batch][n], n: 0-3 i, 4-7 g, 8-11 o
  const int tid = threadIdx.x;
  const int lane = tid & 63;
  const int g = tid >> 6;             // wave = batch group
  const int bid = blockIdx.x;
  const int s = ((bid & 7) << 5) | (bid >> 3);  // XCD-grouped unit slice, bijective on [0,256)
  const int u0 = s * 4;
  const int b0 = g * 16;

  // stage + split W_hh rows for this slice (one-time, both waves cooperate)
  for (int p = tid; p < 1536; p += 128) {
    int n = p >> 7, kq = p & 127;
    int row = (n < 4) ? (u0 + n) : (n < 8) ? (1024 + u0 + (n - 4)) : (2048 + u0 + (n - 8));
    const float* src = Whh + (size_t)row * 1024 + kq * 8;
    f32x4 v0 = *(const f32x4*)src;
    f32x4 v1 = *(const f32x4*)(src + 4);
    s16x4 h4, l4;
#pragma unroll
    for (int j = 0; j < 4; ++j) { short hh, ll; split2(v0[j], hh, ll); h4[j] = hh; l4[j] = ll; }
    *(s16x4*)&Wh[(kq * 12 + n) * 8] = h4;
    *(s16x4*)&Wl[(kq * 12 + n) * 8] = l4;
#pragma unroll
    for (int j = 0; j < 4; ++j) { short hh, ll; split2(v1[j], hh, ll); h4[j] = hh; l4[j] = ll; }
    *(s16x4*)&Wh[(kq * 12 + n) * 8 + 4] = h4;
    *(s16x4*)&Wl[(kq * 12 + n) * 8 + 4] = l4;
  }

  const int m = lane & 15;            // batch-in-group (A row)
  const int q = lane >> 4;            // k quad
  const bool nvalid = m < 12;
  const int eb = (tid >> 2) & 15;     // elementwise batch-in-group
  const int eu = tid & 3;             // elementwise unit
  float c = 0.f;                      // cell state in register across all 512 steps
  __syncthreads();

  for (int t = 0; t < 512; ++t) {
    const int par = t & 1;
    // --- gate-input loads hoisted above matvec: latency hides under MFMA loop ---
    const size_t mrow = (size_t)(b0 + eb) * 512 + t;
    const float xi = Xp[mrow * 3072 + (u0 + eu)];
    const float xg = Xp[mrow * 3072 + 1024 + (u0 + eu)];
    const float xo = Xp[mrow * 3072 + 2048 + (u0 + eu)];

    // --- matvec: D[batch][n] = sum_k h[batch][k] * W[n][k], split-bf16 3-term ---
    const size_t hbase = (size_t)par * 32768 + (size_t)(b0 + m) * 1024 + q * 8;
    f32x4 a0 = {0.f, 0.f, 0.f, 0.f}, a1 = a0, a2 = a0;
#pragma unroll 8
    for (int kc = 0; kc < 32; ++kc) {
      s16x8 ahf = *(const s16x8*)&hhi[hbase + kc * 32];
      s16x8 alf = *(const s16x8*)&hlo[hbase + kc * 32];
      s16x8 bhf = {}, blf = {};
      if (nvalid) {
        bhf = *(const s16x8*)&Wh[(((kc * 4 + q) * 12) + m) * 8];
        blf = *(const s16x8*)&Wl[(((kc * 4 + q) * 12) + m) * 8];
      }
      a0 = __builtin_amdgcn_mfma_f32_16x16x32_bf16(ahf, bhf, a0, 0, 0, 0);
      a1 = __builtin_amdgcn_mfma_f32_16x16x32_bf16(alf, bhf, a1, 0, 0, 0);
      a2 = __builtin_amdgcn_mfma_f32_16x16x32_bf16(ahf, blf, a2, 0, 0, 0);
    }
#pragma unroll
    for (int r = 0; r < 4; ++r)
      red[g][q * 4 + r][m] = a0[r] + a1[r] + a2[r];
    __syncthreads();

    // --- elementwise cell update: one thread per (g,b,u) ---
    {
      float ig = xi + red[g][eb][eu];
      float gg = xg + red[g][eb][4 + eu];
      float og = xo + red[g][eb][8 + eu];
      float si = 1.f / (1.f + expf(-ig));
      float tg = tanhf(gg);
      c += si * tg;
      float so = 1.f / (1.f + expf(-og));
      float h = so * tanhf(c);
      short hh, hl;
      split2(h, hh, hl);
      size_t hw = (size_t)(1 - par) * 32768 + (size_t)(b0 + eb) * 1024 + (u0 + eu);
      hhi[hw] = (ushort_t)hh;
      hlo[hw] = (ushort_t)hl;
      yOut[mrow * 1024 + (u0 + eu)] = h;
      if (t == 511) {
        hOut[(size_t)(b0 + eb) * 1024 + (u0 + eu)] = h;
        cOut[(size_t)(b0 + eb) * 1024 + (u0 + eu)] = c;
      }
    }
    if (t == 511) break;  // no successor step: kernel-end flush publishes outputs

    // ---- two-level grid barrier: master gathers flags, broadcasts epoch ----
    // worker-rel -> flag -> master-acqrel -> epoch -> worker-acq gives transitive
    // happens-before for the h planes with ~500x less poll traffic than R1.
    const int tgt = t + 1;
    __builtin_amdgcn_fence(__ATOMIC_RELEASE, "agent");  // waitcnt + wbl2: h at LLC
    __syncthreads();
    if (bid == 0) {
      if (tid == 0)
        __hip_atomic_store(&bar[0], tgt, __ATOMIC_RELAXED, __HIP_MEMORY_SCOPE_AGENT);
      for (;;) {
        int f0 = __hip_atomic_load(&bar[tid], __ATOMIC_RELAXED, __HIP_MEMORY_SCOPE_AGENT);
        int f1 = __hip_atomic_load(&bar[tid + 128], __ATOMIC_RELAXED, __HIP_MEMORY_SCOPE_AGENT);
        if (__syncthreads_and((f0 >= tgt) && (f1 >= tgt))) break;
        __builtin_amdgcn_s_sleep(2);
      }
      // order flag observations before epoch publish
      __builtin_amdgcn_fence(__ATOMIC_ACQ_REL, "agent");
      if (tid == 0)
        __hip_atomic_store(&bar[256], tgt, __ATOMIC_RELAXED, __HIP_MEMORY_SCOPE_AGENT);
    } else {
      if (tid == 0) {
        __hip_atomic_store(&bar[bid], tgt, __ATOMIC_RELAXED, __HIP_MEMORY_SCOPE_AGENT);
        while (__hip_atomic_load(&bar[256], __ATOMIC_RELAXED, __HIP_MEMORY_SCOPE_AGENT) < tgt)
          __builtin_amdgcn_s_sleep(4);
      }
      __syncthreads();
    }
    __builtin_amdgcn_fence(__ATOMIC_ACQUIRE, "agent"); // inv L2 before reading fresh h
  }
}

// ---------------- host ----------------
extern "C" void kernel_launch(void* const* d_in, const int* in_sizes, int n_in,
                              void* d_out, int out_size, void* d_ws, size_t ws_size,
                              hipStream_t stream) {
  const float* x     = (const float*)d_in[0];
  const float* w_ih0 = (const float*)d_in[1];
  const float* w_hh0 = (const float*)d_in[2];
  const float* b0v   = (const float*)d_in[3];
  const float* w_ihr = (const float*)d_in[4];
  const float* w_hhr = (const float*)d_in[5];
  const float* b_r   = (const float*)d_in[6];
  float* out = (float*)d_out;

  char* ws = (char*)d_ws;
  float*    Xp  = (float*)(ws);                    // 201,326,592 B
  ushort_t* hhi = (ushort_t*)(ws + 201326592);     //     131,072 B
  ushort_t* hlo = (ushort_t*)(ws + 201457664);     //     131,072 B
  int*      bar = (int*)(ws + 201588736);          //       8,192 B (~192.3 MiB total)

  float* yBuf     = out;                 // cur region doubles as inter-layer y staging
  float* hOutBase = out + 16777216;
  float* cOutBase = out + 16777216 + 131072;

  hipMemsetAsync(bar, 0, 8192, stream);

  for (int l = 0; l < 4; ++l) {
    const float* wih  = (l == 0) ? w_ih0 : (w_ihr + (size_t)(l - 1) * 3072 * 1024);
    const float* whh  = (l == 0) ? w_hh0 : (w_hhr + (size_t)(l - 1) * 3072 * 1024);
    const float* bias = (l == 0) ? b0v : (b_r + (size_t)(l - 1) * 3072);
    const int K = (l == 0) ? 512 : 1024;
    const float* Ain = (l == 0) ? x : yBuf;
    dim3 ggrid((16384 / BM) * (3072 / BN));
    k_gemm_split<<<ggrid, 256, 0, stream>>>(Ain, wih, bias, Xp, 16384, 3072, K);
    hipMemsetAsync(hhi, 0, 131072, stream);
    hipMemsetAsync(hlo, 0, 131072, stream);
    float* hO = hOutBase + (size_t)l * 32768;
    float* cO = cOutBase + (size_t)l * 32768;
    int* barL = bar + l * 512;   // flags[256] + epoch[1] per layer; fresh zeroed region
    void* args[] = { (void*)&Xp, (void*)&whh, (void*)&hhi, (void*)&hlo, (void*)&yBuf,
                     (void*)&hO, (void*)&cO, (void*)&barL };
    if (hipLaunchCooperativeKernel((void*)k_recurrent, dim3(256), dim3(128),
                                   args, 0, stream) != hipSuccess) {
      // fallback: plain launch (256 blocks, 50KB LDS, 128 thr -> all co-resident)
      k_recurrent<<<dim3(256), dim3(128), 0, stream>>>(Xp, whh, hhi, hlo, yBuf,
                                                       hO, cO, barL);
    }
  }
}

// Round 3
// 39122.501 us; speedup vs baseline: 2.6387x; 1.3468x over previous
//
#include <hip/hip_runtime.h>

// DeepLSTM: B=32, S=512, IN=512, H=1024, 3H=3072, L=4
// out (fp32): cur [32][512][1024] | h_finals [4][32][1024] | c_finals [4][32][1024]
// ws (~192 MiB): Xp fp32 | hbuf (packed hi|lo words) | bar(flags+epoch)
// Precision: split-bf16 (hi+lo) 3-term MFMA everywhere (~2^-16 rel); Xp fp32;
// inter-layer y fp32 staged in d_out's cur region; h carried as packed (hi,lo) bf16
// words; c in fp32 register.
// R1: distributed-flag barrier replaced 512-way same-line fetch_add.
// R2: master/broadcast barrier killed the poll storm. Step time barely moved ->
//     polls were not the bottleneck.
// R3: kill the per-step full-L2 maintenance. The agent release/acquire fences
//     compiled to buffer_wbl2 sc1 + buffer_inv sc1 = whole-4MiB-L2 writeback +
//     invalidate per block per step (~15-20us of the 23.5us step). Only h (256KB)
//     and the barrier words need mid-kernel coherence, so those now use agent-scope
//     (sc1, L2-bypass) relaxed atomics exclusively: h packed to one uint word/unit
//     (4B atomic store), matvec reads h via u64 atomic loads + VALU unpack.
//     Ordering = s_waitcnt vmcnt(0) + __syncthreads before flag store; per-address
//     LLC serialization does the rest. No wbl2/inv anywhere in the step loop.
//     Xp/yOut/hOut/cOut stay normally cached (cross-kernel only, flushed at end).

typedef unsigned short ushort_t;
typedef __attribute__((ext_vector_type(4))) float f32x4;
typedef __attribute__((ext_vector_type(8))) short s16x8;
typedef __attribute__((ext_vector_type(4))) short s16x4;

__device__ __forceinline__ unsigned short f2bf(float f) {
  union { float f; unsigned u; } v; v.f = f;
  unsigned r = (v.u + 0x7fffu + ((v.u >> 16) & 1u)) >> 16;
  return (unsigned short)r;
}
__device__ __forceinline__ float bf2f(unsigned short h) {
  union { unsigned u; float f; } v; v.u = ((unsigned)h) << 16; return v.f;
}
__device__ __forceinline__ void split2(float x, short& hi, short& lo) {
  unsigned short h = f2bf(x);
  hi = (short)h;
  lo = (short)f2bf(x - bf2f(h));
}

// unpack 8 packed h-words (hi<<16|lo) from four u64 into hi/lo bf16 fragments
__device__ __forceinline__ void unpack8(unsigned long long d0, unsigned long long d1,
                                        unsigned long long d2, unsigned long long d3,
                                        s16x8& hi, s16x8& lo) {
  unsigned w0 = (unsigned)d0, w1 = (unsigned)(d0 >> 32);
  unsigned w2 = (unsigned)d1, w3 = (unsigned)(d1 >> 32);
  unsigned w4 = (unsigned)d2, w5 = (unsigned)(d2 >> 32);
  unsigned w6 = (unsigned)d3, w7 = (unsigned)(d3 >> 32);
  union { unsigned u[4]; s16x8 v; } H, L;
  H.u[0] = (w0 >> 16) | (w1 & 0xffff0000u); L.u[0] = (w0 & 0xffffu) | (w1 << 16);
  H.u[1] = (w2 >> 16) | (w3 & 0xffff0000u); L.u[1] = (w2 & 0xffffu) | (w3 << 16);
  H.u[2] = (w4 >> 16) | (w5 & 0xffff0000u); L.u[2] = (w4 & 0xffffu) | (w5 << 16);
  H.u[3] = (w6 >> 16) | (w7 & 0xffff0000u); L.u[3] = (w6 & 0xffffu) | (w7 << 16);
  hi = H.v; lo = L.v;
}

// ---------------- split-bf16 GEMM: C[m][n] = sum_k A[m][k]*Bw[n][k] + bias[n] ----------------
// A: fp32 [M][K]; Bw: fp32 [N][K]; C: fp32 [M][N]. BM=BN=128, BK=32. (unchanged)
#define BM 128
#define BN 128
#define BK 32
__global__ __launch_bounds__(256) void k_gemm_split(
    const float* __restrict__ A, const float* __restrict__ Bw,
    const float* __restrict__ bias, float* __restrict__ C,
    int M, int N, int K) {
  __shared__ short Ah[BM * BK], Al[BM * BK];
  __shared__ short Bh[BN * BK], Bl[BN * BK];
  const int tid = threadIdx.x;
  const int nbm = M / BM;
  const int bm = blockIdx.x % nbm;
  const int bn = blockIdx.x / nbm;
  const int lane = tid & 63;
  const int wave = tid >> 6;
  const int wm = (wave & 1) * 64;
  const int wn = (wave >> 1) * 64;
  const int q = lane >> 4;
  f32x4 acc[4][4] = {};
  const int nk = K / BK;
  for (int kt = 0; kt < nk; ++kt) {
    __syncthreads();
    const int kb = kt * BK;
#pragma unroll
    for (int i = 0; i < 4; ++i) {
      int idx = tid + i * 256;            // 0..1023
      int row = idx >> 3, c4 = (idx & 7) * 4;
      f32x4 ta = *(const f32x4*)(A + (size_t)(bm * BM + row) * K + kb + c4);
      s16x4 h4, l4;
#pragma unroll
      for (int j = 0; j < 4; ++j) { short hh, ll; split2(ta[j], hh, ll); h4[j] = hh; l4[j] = ll; }
      *(s16x4*)&Ah[row * BK + c4] = h4;
      *(s16x4*)&Al[row * BK + c4] = l4;
      f32x4 tb = *(const f32x4*)(Bw + (size_t)(bn * BN + row) * K + kb + c4);
#pragma unroll
      for (int j = 0; j < 4; ++j) { short hh, ll; split2(tb[j], hh, ll); h4[j] = hh; l4[j] = ll; }
      *(s16x4*)&Bh[row * BK + c4] = h4;
      *(s16x4*)&Bl[row * BK + c4] = l4;
    }
    __syncthreads();
    s16x8 ah[4], al[4], bh[4], bl[4];
#pragma unroll
    for (int i = 0; i < 4; ++i) {
      int r = (wm + i * 16 + (lane & 15)) * BK + q * 8;
      ah[i] = *(const s16x8*)&Ah[r];
      al[i] = *(const s16x8*)&Al[r];
      int rb = (wn + i * 16 + (lane & 15)) * BK + q * 8;
      bh[i] = *(const s16x8*)&Bh[rb];
      bl[i] = *(const s16x8*)&Bl[rb];
    }
#pragma unroll
    for (int mi = 0; mi < 4; ++mi)
#pragma unroll
      for (int ni = 0; ni < 4; ++ni) {
        acc[mi][ni] = __builtin_amdgcn_mfma_f32_16x16x32_bf16(ah[mi], bh[ni], acc[mi][ni], 0, 0, 0);
        acc[mi][ni] = __builtin_amdgcn_mfma_f32_16x16x32_bf16(al[mi], bh[ni], acc[mi][ni], 0, 0, 0);
        acc[mi][ni] = __builtin_amdgcn_mfma_f32_16x16x32_bf16(ah[mi], bl[ni], acc[mi][ni], 0, 0, 0);
      }
  }
#pragma unroll
  for (int mi = 0; mi < 4; ++mi)
#pragma unroll
    for (int ni = 0; ni < 4; ++ni) {
      int col = bn * BN + wn + ni * 16 + (lane & 15);
      float bv = bias[col];
#pragma unroll
      for (int r = 0; r < 4; ++r) {
        int row = bm * BM + wm + mi * 16 + q * 4 + r;
        C[(size_t)row * N + col] = acc[mi][ni][r] + bv;
      }
    }
}

// ---------------- persistent recurrent kernel (one layer, 512 steps) ----------------
// 256 blocks x 128 threads (2 waves). Wave g in {0,1}: batch group g*16..g*16+15.
// Block owns 4 hidden units u0..u0+3 (all 3 gates): s = (bid&7)*32 + (bid>>3) so
// consecutive unit-slices land on the same XCD (Xp/yOut 64B-line sharing in L2).
// LDS: split W_hh tile, 12 rows x K=1024, hi+lo = 48KB (shared by both waves) + red 2KB.
// hbuf: uint [2][32][1024], word = (bf16_hi<<16)|bf16_lo. All hbuf traffic is
// agent-scope relaxed atomic (sc1 -> LLC), so NO cache maintenance in the loop.
// bar layout (per layer, 512 ints): [0..255] per-block step flags, [256] epoch word.
__global__ __launch_bounds__(128) void k_recurrent(
    const float* __restrict__ Xp,     // [16384][3072] fp32: x@Wih^T + b (rows m=b*512+t)
    const float* __restrict__ Whh,    // [3072][1024] fp32 (original weights)
    unsigned* __restrict__ hbuf,      // [2][32][1024] packed h words (pre-zeroed)
    float* __restrict__ yOut,         // [32][512][1024] fp32: layer output (cur region)
    float* __restrict__ hOut,         // [32][1024] f32
    float* __restrict__ cOut,         // [32][1024] f32
    int* __restrict__ bar)            // [512] ints: flags[256] + epoch, zeroed
{
  __shared__ short Wh[128 * 12 * 8];  // [kq][n][8] hi, 24 KB
  __shared__ short Wl[128 * 12 * 8];  // lo, 24 KB
  __shared__ float red[2][16][16];    // [g][batch][n], n: 0-3 i, 4-7 g, 8-11 o
  const int tid = threadIdx.x;
  const int lane = tid & 63;
  const int g = tid >> 6;             // wave = batch group
  const int bid = blockIdx.x;
  const int s = ((bid & 7) << 5) | (bid >> 3);  // XCD-grouped unit slice, bijective on [0,256)
  const int u0 = s * 4;
  const int b0 = g * 16;

  // stage + split W_hh rows for this slice (one-time, both waves cooperate)
  for (int p = tid; p < 1536; p += 128) {
    int n = p >> 7, kq = p & 127;
    int row = (n < 4) ? (u0 + n) : (n < 8) ? (1024 + u0 + (n - 4)) : (2048 + u0 + (n - 8));
    const float* src = Whh + (size_t)row * 1024 + kq * 8;
    f32x4 v0 = *(const f32x4*)src;
    f32x4 v1 = *(const f32x4*)(src + 4);
    s16x4 h4, l4;
#pragma unroll
    for (int j = 0; j < 4; ++j) { short hh, ll; split2(v0[j], hh, ll); h4[j] = hh; l4[j] = ll; }
    *(s16x4*)&Wh[(kq * 12 + n) * 8] = h4;
    *(s16x4*)&Wl[(kq * 12 + n) * 8] = l4;
#pragma unroll
    for (int j = 0; j < 4; ++j) { short hh, ll; split2(v1[j], hh, ll); h4[j] = hh; l4[j] = ll; }
    *(s16x4*)&Wh[(kq * 12 + n) * 8 + 4] = h4;
    *(s16x4*)&Wl[(kq * 12 + n) * 8 + 4] = l4;
  }

  const int m = lane & 15;            // batch-in-group (A row)
  const int q = lane >> 4;            // k quad
  const bool nvalid = m < 12;
  const int eb = (tid >> 2) & 15;     // elementwise batch-in-group
  const int eu = tid & 3;             // elementwise unit
  float c = 0.f;                      // cell state in register across all 512 steps
  __syncthreads();

  for (int t = 0; t < 512; ++t) {
    const int par = t & 1;
    // --- gate-input loads hoisted above matvec: latency hides under MFMA loop ---
    const size_t mrow = (size_t)(b0 + eb) * 512 + t;
    const float xi = Xp[mrow * 3072 + (u0 + eu)];
    const float xg = Xp[mrow * 3072 + 1024 + (u0 + eu)];
    const float xo = Xp[mrow * 3072 + 2048 + (u0 + eu)];

    // --- matvec: D[batch][n] = sum_k h[batch][k] * W[n][k], split-bf16 3-term ---
    // h words read via agent-scope (sc1) u64 atomic loads: always-fresh from LLC,
    // no L2 invalidate needed. Word index, /2 for u64 index.
    const size_t hb2 = ((size_t)par * 32768 + (size_t)(b0 + m) * 1024 + q * 8) >> 1;
    const unsigned long long* hp64 = (const unsigned long long*)hbuf;
    f32x4 a0 = {0.f, 0.f, 0.f, 0.f}, a1 = a0, a2 = a0;
#pragma unroll 8
    for (int kc = 0; kc < 32; ++kc) {
      const unsigned long long* p = hp64 + hb2 + kc * 16;
      unsigned long long d0 = __hip_atomic_load(p + 0, __ATOMIC_RELAXED, __HIP_MEMORY_SCOPE_AGENT);
      unsigned long long d1 = __hip_atomic_load(p + 1, __ATOMIC_RELAXED, __HIP_MEMORY_SCOPE_AGENT);
      unsigned long long d2 = __hip_atomic_load(p + 2, __ATOMIC_RELAXED, __HIP_MEMORY_SCOPE_AGENT);
      unsigned long long d3 = __hip_atomic_load(p + 3, __ATOMIC_RELAXED, __HIP_MEMORY_SCOPE_AGENT);
      s16x8 ahf, alf;
      unpack8(d0, d1, d2, d3, ahf, alf);
      s16x8 bhf = {}, blf = {};
      if (nvalid) {
        bhf = *(const s16x8*)&Wh[(((kc * 4 + q) * 12) + m) * 8];
        blf = *(const s16x8*)&Wl[(((kc * 4 + q) * 12) + m) * 8];
      }
      a0 = __builtin_amdgcn_mfma_f32_16x16x32_bf16(ahf, bhf, a0, 0, 0, 0);
      a1 = __builtin_amdgcn_mfma_f32_16x16x32_bf16(alf, bhf, a1, 0, 0, 0);
      a2 = __builtin_amdgcn_mfma_f32_16x16x32_bf16(ahf, blf, a2, 0, 0, 0);
    }
#pragma unroll
    for (int r = 0; r < 4; ++r)
      red[g][q * 4 + r][m] = a0[r] + a1[r] + a2[r];
    __syncthreads();

    // --- elementwise cell update: one thread per (g,b,u) ---
    {
      float ig = xi + red[g][eb][eu];
      float gg = xg + red[g][eb][4 + eu];
      float og = xo + red[g][eb][8 + eu];
      float si = 1.f / (1.f + expf(-ig));
      float tg = tanhf(gg);
      c += si * tg;
      float so = 1.f / (1.f + expf(-og));
      float h = so * tanhf(c);
      short hh, hl;
      split2(h, hh, hl);
      unsigned hword = ((unsigned)(unsigned short)hh << 16) | (unsigned)(unsigned short)hl;
      size_t hw = (size_t)(1 - par) * 32768 + (size_t)(b0 + eb) * 1024 + (u0 + eu);
      __hip_atomic_store(&hbuf[hw], hword, __ATOMIC_RELAXED, __HIP_MEMORY_SCOPE_AGENT);
      yOut[mrow * 1024 + (u0 + eu)] = h;
      if (t == 511) {
        hOut[(size_t)(b0 + eb) * 1024 + (u0 + eu)] = h;
        cOut[(size_t)(b0 + eb) * 1024 + (u0 + eu)] = c;
      }
    }
    if (t == 511) break;  // no successor step: kernel-end flush publishes outputs

    // ---- two-level grid barrier, zero cache-maintenance ----
    // Own wave's sc1 h-stores must be LLC-acked before the flag store (vmcnt is
    // per-wave; syncthreads covers the sibling wave). All barrier words are sc1,
    // so per-address LLC serialization gives transitive happens-before for h.
    const int tgt = t + 1;
    asm volatile("s_waitcnt vmcnt(0)" ::: "memory");
    __syncthreads();
    if (bid == 0) {
      if (tid == 0)
        __hip_atomic_store(&bar[0], tgt, __ATOMIC_RELAXED, __HIP_MEMORY_SCOPE_AGENT);
      for (;;) {
        int f0 = __hip_atomic_load(&bar[tid], __ATOMIC_RELAXED, __HIP_MEMORY_SCOPE_AGENT);
        int f1 = __hip_atomic_load(&bar[tid + 128], __ATOMIC_RELAXED, __HIP_MEMORY_SCOPE_AGENT);
        if (__syncthreads_and((f0 >= tgt) && (f1 >= tgt))) break;
        __builtin_amdgcn_s_sleep(2);
      }
      if (tid == 0)
        __hip_atomic_store(&bar[256], tgt, __ATOMIC_RELAXED, __HIP_MEMORY_SCOPE_AGENT);
    } else {
      if (tid == 0) {
        __hip_atomic_store(&bar[bid], tgt, __ATOMIC_RELAXED, __HIP_MEMORY_SCOPE_AGENT);
        while (__hip_atomic_load(&bar[256], __ATOMIC_RELAXED, __HIP_MEMORY_SCOPE_AGENT) < tgt)
          __builtin_amdgcn_s_sleep(2);
      }
      __syncthreads();
    }
    asm volatile("" ::: "memory");  // compiler barrier: no hoisting h loads above poll
  }
}

// ---------------- host ----------------
extern "C" void kernel_launch(void* const* d_in, const int* in_sizes, int n_in,
                              void* d_out, int out_size, void* d_ws, size_t ws_size,
                              hipStream_t stream) {
  const float* x     = (const float*)d_in[0];
  const float* w_ih0 = (const float*)d_in[1];
  const float* w_hh0 = (const float*)d_in[2];
  const float* b0v   = (const float*)d_in[3];
  const float* w_ihr = (const float*)d_in[4];
  const float* w_hhr = (const float*)d_in[5];
  const float* b_r   = (const float*)d_in[6];
  float* out = (float*)d_out;

  char* ws = (char*)d_ws;
  float*    Xp   = (float*)(ws);                   // 201,326,592 B
  unsigned* hbuf = (unsigned*)(ws + 201326592);    //     262,144 B (packed h words)
  int*      bar  = (int*)(ws + 201588736);         //       8,192 B (~192.3 MiB total)

  float* yBuf     = out;                 // cur region doubles as inter-layer y staging
  float* hOutBase = out + 16777216;
  float* cOutBase = out + 16777216 + 131072;

  hipMemsetAsync(bar, 0, 8192, stream);

  for (int l = 0; l < 4; ++l) {
    const float* wih  = (l == 0) ? w_ih0 : (w_ihr + (size_t)(l - 1) * 3072 * 1024);
    const float* whh  = (l == 0) ? w_hh0 : (w_hhr + (size_t)(l - 1) * 3072 * 1024);
    const float* bias = (l == 0) ? b0v : (b_r + (size_t)(l - 1) * 3072);
    const int K = (l == 0) ? 512 : 1024;
    const float* Ain = (l == 0) ? x : yBuf;
    dim3 ggrid((16384 / BM) * (3072 / BN));
    k_gemm_split<<<ggrid, 256, 0, stream>>>(Ain, wih, bias, Xp, 16384, 3072, K);
    hipMemsetAsync(hbuf, 0, 262144, stream);
    float* hO = hOutBase + (size_t)l * 32768;
    float* cO = cOutBase + (size_t)l * 32768;
    int* barL = bar + l * 512;   // flags[256] + epoch[1] per layer; fresh zeroed region
    void* args[] = { (void*)&Xp, (void*)&whh, (void*)&hbuf, (void*)&yBuf,
                     (void*)&hO, (void*)&cO, (void*)&barL };
    if (hipLaunchCooperativeKernel((void*)k_recurrent, dim3(256), dim3(128),
                                   args, 0, stream) != hipSuccess) {
      // fallback: plain launch (256 blocks, 50KB LDS, 128 thr -> all co-resident)
      k_recurrent<<<dim3(256), dim3(128), 0, stream>>>(Xp, whh, hbuf, yBuf,
                                                       hO, cO, barL);
    }
  }
}

// Round 4
// 23459.018 us; speedup vs baseline: 4.4006x; 1.6677x over previous
//
#include <hip/hip_runtime.h>

// DeepLSTM: B=32, S=512, IN=512, H=1024, 3H=3072, L=4
// out (fp32): cur [32][512][1024] | h_finals [4][32][1024] | c_finals [4][32][1024]
// ws (~192 MiB): Xp fp32 | hbuf (packed hi|lo words) | bar(flags+epoch)
// Precision: split-bf16 (hi+lo) 3-term MFMA everywhere (~2^-16 rel); Xp fp32;
// inter-layer y fp32 staged in d_out's cur region; h carried as packed (hi,lo) bf16
// words; c in fp32 register.
// R1: distributed-flag barrier replaced 512-way same-line fetch_add.
// R2: master/broadcast barrier killed the poll storm (polls weren't dominant).
// R3: all mid-kernel coherence moved to agent-scope (sc1) relaxed atomics; deleted
//     per-step full-L2 wbl2/inv. 23.5 -> 15.9 us/step, variance gone.
// R4: kill the LLC hot-line storm on h reads. All 256 blocks swept the same 128KB
//     h-plane in the same kc order -> ~256 concurrent readers per line serializing
//     at the LLC slice (sc1 bypasses L2; effective read rate only ~2 TB/s).
//     (a) stagger each block's kc start by its slice id (one stagger offset per
//     block within each XCD) -> ~8 concurrent readers/line; (b) unroll 16 for ~2x
//     more loads in flight against ~900cy LLC latency; (c) s_sleep(2)->(1) polls.

typedef unsigned short ushort_t;
typedef __attribute__((ext_vector_type(4))) float f32x4;
typedef __attribute__((ext_vector_type(8))) short s16x8;
typedef __attribute__((ext_vector_type(4))) short s16x4;

__device__ __forceinline__ unsigned short f2bf(float f) {
  union { float f; unsigned u; } v; v.f = f;
  unsigned r = (v.u + 0x7fffu + ((v.u >> 16) & 1u)) >> 16;
  return (unsigned short)r;
}
__device__ __forceinline__ float bf2f(unsigned short h) {
  union { unsigned u; float f; } v; v.u = ((unsigned)h) << 16; return v.f;
}
__device__ __forceinline__ void split2(float x, short& hi, short& lo) {
  unsigned short h = f2bf(x);
  hi = (short)h;
  lo = (short)f2bf(x - bf2f(h));
}

// unpack 8 packed h-words (hi<<16|lo) from four u64 into hi/lo bf16 fragments
__device__ __forceinline__ void unpack8(unsigned long long d0, unsigned long long d1,
                                        unsigned long long d2, unsigned long long d3,
                                        s16x8& hi, s16x8& lo) {
  unsigned w0 = (unsigned)d0, w1 = (unsigned)(d0 >> 32);
  unsigned w2 = (unsigned)d1, w3 = (unsigned)(d1 >> 32);
  unsigned w4 = (unsigned)d2, w5 = (unsigned)(d2 >> 32);
  unsigned w6 = (unsigned)d3, w7 = (unsigned)(d3 >> 32);
  union { unsigned u[4]; s16x8 v; } H, L;
  H.u[0] = (w0 >> 16) | (w1 & 0xffff0000u); L.u[0] = (w0 & 0xffffu) | (w1 << 16);
  H.u[1] = (w2 >> 16) | (w3 & 0xffff0000u); L.u[1] = (w2 & 0xffffu) | (w3 << 16);
  H.u[2] = (w4 >> 16) | (w5 & 0xffff0000u); L.u[2] = (w4 & 0xffffu) | (w5 << 16);
  H.u[3] = (w6 >> 16) | (w7 & 0xffff0000u); L.u[3] = (w6 & 0xffffu) | (w7 << 16);
  hi = H.v; lo = L.v;
}

// ---------------- split-bf16 GEMM: C[m][n] = sum_k A[m][k]*Bw[n][k] + bias[n] ----------------
// A: fp32 [M][K]; Bw: fp32 [N][K]; C: fp32 [M][N]. BM=BN=128, BK=32. (unchanged)
#define BM 128
#define BN 128
#define BK 32
__global__ __launch_bounds__(256) void k_gemm_split(
    const float* __restrict__ A, const float* __restrict__ Bw,
    const float* __restrict__ bias, float* __restrict__ C,
    int M, int N, int K) {
  __shared__ short Ah[BM * BK], Al[BM * BK];
  __shared__ short Bh[BN * BK], Bl[BN * BK];
  const int tid = threadIdx.x;
  const int nbm = M / BM;
  const int bm = blockIdx.x % nbm;
  const int bn = blockIdx.x / nbm;
  const int lane = tid & 63;
  const int wave = tid >> 6;
  const int wm = (wave & 1) * 64;
  const int wn = (wave >> 1) * 64;
  const int q = lane >> 4;
  f32x4 acc[4][4] = {};
  const int nk = K / BK;
  for (int kt = 0; kt < nk; ++kt) {
    __syncthreads();
    const int kb = kt * BK;
#pragma unroll
    for (int i = 0; i < 4; ++i) {
      int idx = tid + i * 256;            // 0..1023
      int row = idx >> 3, c4 = (idx & 7) * 4;
      f32x4 ta = *(const f32x4*)(A + (size_t)(bm * BM + row) * K + kb + c4);
      s16x4 h4, l4;
#pragma unroll
      for (int j = 0; j < 4; ++j) { short hh, ll; split2(ta[j], hh, ll); h4[j] = hh; l4[j] = ll; }
      *(s16x4*)&Ah[row * BK + c4] = h4;
      *(s16x4*)&Al[row * BK + c4] = l4;
      f32x4 tb = *(const f32x4*)(Bw + (size_t)(bn * BN + row) * K + kb + c4);
#pragma unroll
      for (int j = 0; j < 4; ++j) { short hh, ll; split2(tb[j], hh, ll); h4[j] = hh; l4[j] = ll; }
      *(s16x4*)&Bh[row * BK + c4] = h4;
      *(s16x4*)&Bl[row * BK + c4] = l4;
    }
    __syncthreads();
    s16x8 ah[4], al[4], bh[4], bl[4];
#pragma unroll
    for (int i = 0; i < 4; ++i) {
      int r = (wm + i * 16 + (lane & 15)) * BK + q * 8;
      ah[i] = *(const s16x8*)&Ah[r];
      al[i] = *(const s16x8*)&Al[r];
      int rb = (wn + i * 16 + (lane & 15)) * BK + q * 8;
      bh[i] = *(const s16x8*)&Bh[rb];
      bl[i] = *(const s16x8*)&Bl[rb];
    }
#pragma unroll
    for (int mi = 0; mi < 4; ++mi)
#pragma unroll
      for (int ni = 0; ni < 4; ++ni) {
        acc[mi][ni] = __builtin_amdgcn_mfma_f32_16x16x32_bf16(ah[mi], bh[ni], acc[mi][ni], 0, 0, 0);
        acc[mi][ni] = __builtin_amdgcn_mfma_f32_16x16x32_bf16(al[mi], bh[ni], acc[mi][ni], 0, 0, 0);
        acc[mi][ni] = __builtin_amdgcn_mfma_f32_16x16x32_bf16(ah[mi], bl[ni], acc[mi][ni], 0, 0, 0);
      }
  }
#pragma unroll
  for (int mi = 0; mi < 4; ++mi)
#pragma unroll
    for (int ni = 0; ni < 4; ++ni) {
      int col = bn * BN + wn + ni * 16 + (lane & 15);
      float bv = bias[col];
#pragma unroll
      for (int r = 0; r < 4; ++r) {
        int row = bm * BM + wm + mi * 16 + q * 4 + r;
        C[(size_t)row * N + col] = acc[mi][ni][r] + bv;
      }
    }
}

// ---------------- persistent recurrent kernel (one layer, 512 steps) ----------------
// 256 blocks x 128 threads (2 waves). Wave g in {0,1}: batch group g*16..g*16+15.
// Block owns 4 hidden units u0..u0+3 (all 3 gates): s = (bid&7)*32 + (bid>>3) so
// consecutive unit-slices land on the same XCD (Xp/yOut 64B-line sharing in L2).
// LDS: split W_hh tile, 12 rows x K=1024, hi+lo = 48KB (shared by both waves) + red 2KB.
// hbuf: uint [2][32][1024], word = (bf16_hi<<16)|bf16_lo. All hbuf traffic is
// agent-scope relaxed atomic (sc1 -> LLC), so NO cache maintenance in the loop.
// bar layout (per layer, 512 ints): [0..255] per-block step flags, [256] epoch word.
__global__ __launch_bounds__(128) void k_recurrent(
    const float* __restrict__ Xp,     // [16384][3072] fp32: x@Wih^T + b (rows m=b*512+t)
    const float* __restrict__ Whh,    // [3072][1024] fp32 (original weights)
    unsigned* __restrict__ hbuf,      // [2][32][1024] packed h words (pre-zeroed)
    float* __restrict__ yOut,         // [32][512][1024] fp32: layer output (cur region)
    float* __restrict__ hOut,         // [32][1024] f32
    float* __restrict__ cOut,         // [32][1024] f32
    int* __restrict__ bar)            // [512] ints: flags[256] + epoch, zeroed
{
  __shared__ short Wh[128 * 12 * 8];  // [kq][n][8] hi, 24 KB
  __shared__ short Wl[128 * 12 * 8];  // lo, 24 KB
  __shared__ float red[2][16][16];    // [g][batch][n], n: 0-3 i, 4-7 g, 8-11 o
  const int tid = threadIdx.x;
  const int lane = tid & 63;
  const int g = tid >> 6;             // wave = batch group
  const int bid = blockIdx.x;
  const int s = ((bid & 7) << 5) | (bid >> 3);  // XCD-grouped unit slice, bijective on [0,256)
  const int u0 = s * 4;
  const int b0 = g * 16;

  // stage + split W_hh rows for this slice (one-time, both waves cooperate)
  for (int p = tid; p < 1536; p += 128) {
    int n = p >> 7, kq = p & 127;
    int row = (n < 4) ? (u0 + n) : (n < 8) ? (1024 + u0 + (n - 4)) : (2048 + u0 + (n - 8));
    const float* src = Whh + (size_t)row * 1024 + kq * 8;
    f32x4 v0 = *(const f32x4*)src;
    f32x4 v1 = *(const f32x4*)(src + 4);
    s16x4 h4, l4;
#pragma unroll
    for (int j = 0; j < 4; ++j) { short hh, ll; split2(v0[j], hh, ll); h4[j] = hh; l4[j] = ll; }
    *(s16x4*)&Wh[(kq * 12 + n) * 8] = h4;
    *(s16x4*)&Wl[(kq * 12 + n) * 8] = l4;
#pragma unroll
    for (int j = 0; j < 4; ++j) { short hh, ll; split2(v1[j], hh, ll); h4[j] = hh; l4[j] = ll; }
    *(s16x4*)&Wh[(kq * 12 + n) * 8 + 4] = h4;
    *(s16x4*)&Wl[(kq * 12 + n) * 8 + 4] = l4;
  }

  const int m = lane & 15;            // batch-in-group (A row)
  const int q = lane >> 4;            // k quad
  const bool nvalid = m < 12;
  const int eb = (tid >> 2) & 15;     // elementwise batch-in-group
  const int eu = tid & 3;             // elementwise unit
  const int kc0 = s & 31;             // per-block kc stagger: spreads the 32 blocks of
                                      // each XCD across the 32 kc-stripes of the h-plane
  float c = 0.f;                      // cell state in register across all 512 steps
  __syncthreads();

  for (int t = 0; t < 512; ++t) {
    const int par = t & 1;
    // --- gate-input loads hoisted above matvec: latency hides under MFMA loop ---
    const size_t mrow = (size_t)(b0 + eb) * 512 + t;
    const float xi = Xp[mrow * 3072 + (u0 + eu)];
    const float xg = Xp[mrow * 3072 + 1024 + (u0 + eu)];
    const float xo = Xp[mrow * 3072 + 2048 + (u0 + eu)];

    // --- matvec: D[batch][n] = sum_k h[batch][k] * W[n][k], split-bf16 3-term ---
    // h words read via agent-scope (sc1) u64 atomic loads: always-fresh from LLC,
    // no L2 invalidate needed. kc order rotated by kc0 per block (anti-hot-line).
    const size_t hb2 = ((size_t)par * 32768 + (size_t)(b0 + m) * 1024 + q * 8) >> 1;
    const unsigned long long* hp64 = (const unsigned long long*)hbuf;
    f32x4 a0 = {0.f, 0.f, 0.f, 0.f}, a1 = a0, a2 = a0;
#pragma unroll 16
    for (int kci = 0; kci < 32; ++kci) {
      const int kc = (kci + kc0) & 31;
      const unsigned long long* p = hp64 + hb2 + kc * 16;
      unsigned long long d0 = __hip_atomic_load(p + 0, __ATOMIC_RELAXED, __HIP_MEMORY_SCOPE_AGENT);
      unsigned long long d1 = __hip_atomic_load(p + 1, __ATOMIC_RELAXED, __HIP_MEMORY_SCOPE_AGENT);
      unsigned long long d2 = __hip_atomic_load(p + 2, __ATOMIC_RELAXED, __HIP_MEMORY_SCOPE_AGENT);
      unsigned long long d3 = __hip_atomic_load(p + 3, __ATOMIC_RELAXED, __HIP_MEMORY_SCOPE_AGENT);
      s16x8 ahf, alf;
      unpack8(d0, d1, d2, d3, ahf, alf);
      s16x8 bhf = {}, blf = {};
      if (nvalid) {
        bhf = *(const s16x8*)&Wh[(((kc * 4 + q) * 12) + m) * 8];
        blf = *(const s16x8*)&Wl[(((kc * 4 + q) * 12) + m) * 8];
      }
      a0 = __builtin_amdgcn_mfma_f32_16x16x32_bf16(ahf, bhf, a0, 0, 0, 0);
      a1 = __builtin_amdgcn_mfma_f32_16x16x32_bf16(alf, bhf, a1, 0, 0, 0);
      a2 = __builtin_amdgcn_mfma_f32_16x16x32_bf16(ahf, blf, a2, 0, 0, 0);
    }
#pragma unroll
    for (int r = 0; r < 4; ++r)
      red[g][q * 4 + r][m] = a0[r] + a1[r] + a2[r];
    __syncthreads();

    // --- elementwise cell update: one thread per (g,b,u) ---
    {
      float ig = xi + red[g][eb][eu];
      float gg = xg + red[g][eb][4 + eu];
      float og = xo + red[g][eb][8 + eu];
      float si = 1.f / (1.f + expf(-ig));
      float tg = tanhf(gg);
      c += si * tg;
      float so = 1.f / (1.f + expf(-og));
      float h = so * tanhf(c);
      short hh, hl;
      split2(h, hh, hl);
      unsigned hword = ((unsigned)(unsigned short)hh << 16) | (unsigned)(unsigned short)hl;
      size_t hw = (size_t)(1 - par) * 32768 + (size_t)(b0 + eb) * 1024 + (u0 + eu);
      __hip_atomic_store(&hbuf[hw], hword, __ATOMIC_RELAXED, __HIP_MEMORY_SCOPE_AGENT);
      yOut[mrow * 1024 + (u0 + eu)] = h;
      if (t == 511) {
        hOut[(size_t)(b0 + eb) * 1024 + (u0 + eu)] = h;
        cOut[(size_t)(b0 + eb) * 1024 + (u0 + eu)] = c;
      }
    }
    if (t == 511) break;  // no successor step: kernel-end flush publishes outputs

    // ---- two-level grid barrier, zero cache-maintenance ----
    // Own wave's sc1 h-stores must be LLC-acked before the flag store (vmcnt is
    // per-wave; syncthreads covers the sibling wave). All barrier words are sc1,
    // so per-address LLC serialization gives transitive happens-before for h.
    const int tgt = t + 1;
    asm volatile("s_waitcnt vmcnt(0)" ::: "memory");
    __syncthreads();
    if (bid == 0) {
      if (tid == 0)
        __hip_atomic_store(&bar[0], tgt, __ATOMIC_RELAXED, __HIP_MEMORY_SCOPE_AGENT);
      for (;;) {
        int f0 = __hip_atomic_load(&bar[tid], __ATOMIC_RELAXED, __HIP_MEMORY_SCOPE_AGENT);
        int f1 = __hip_atomic_load(&bar[tid + 128], __ATOMIC_RELAXED, __HIP_MEMORY_SCOPE_AGENT);
        if (__syncthreads_and((f0 >= tgt) && (f1 >= tgt))) break;
        __builtin_amdgcn_s_sleep(1);
      }
      if (tid == 0)
        __hip_atomic_store(&bar[256], tgt, __ATOMIC_RELAXED, __HIP_MEMORY_SCOPE_AGENT);
    } else {
      if (tid == 0) {
        __hip_atomic_store(&bar[bid], tgt, __ATOMIC_RELAXED, __HIP_MEMORY_SCOPE_AGENT);
        while (__hip_atomic_load(&bar[256], __ATOMIC_RELAXED, __HIP_MEMORY_SCOPE_AGENT) < tgt)
          __builtin_amdgcn_s_sleep(1);
      }
      __syncthreads();
    }
    asm volatile("" ::: "memory");  // compiler barrier: no hoisting h loads above poll
  }
}

// ---------------- host ----------------
extern "C" void kernel_launch(void* const* d_in, const int* in_sizes, int n_in,
                              void* d_out, int out_size, void* d_ws, size_t ws_size,
                              hipStream_t stream) {
  const float* x     = (const float*)d_in[0];
  const float* w_ih0 = (const float*)d_in[1];
  const float* w_hh0 = (const float*)d_in[2];
  const float* b0v   = (const float*)d_in[3];
  const float* w_ihr = (const float*)d_in[4];
  const float* w_hhr = (const float*)d_in[5];
  const float* b_r   = (const float*)d_in[6];
  float* out = (float*)d_out;

  char* ws = (char*)d_ws;
  float*    Xp   = (float*)(ws);                   // 201,326,592 B
  unsigned* hbuf = (unsigned*)(ws + 201326592);    //     262,144 B (packed h words)
  int*      bar  = (int*)(ws + 201588736);         //       8,192 B (~192.3 MiB total)

  float* yBuf     = out;                 // cur region doubles as inter-layer y staging
  float* hOutBase = out + 16777216;
  float* cOutBase = out + 16777216 + 131072;

  hipMemsetAsync(bar, 0, 8192, stream);

  for (int l = 0; l < 4; ++l) {
    const float* wih  = (l == 0) ? w_ih0 : (w_ihr + (size_t)(l - 1) * 3072 * 1024);
    const float* whh  = (l == 0) ? w_hh0 : (w_hhr + (size_t)(l - 1) * 3072 * 1024);
    const float* bias = (l == 0) ? b0v : (b_r + (size_t)(l - 1) * 3072);
    const int K = (l == 0) ? 512 : 1024;
    const float* Ain = (l == 0) ? x : yBuf;
    dim3 ggrid((16384 / BM) * (3072 / BN));
    k_gemm_split<<<ggrid, 256, 0, stream>>>(Ain, wih, bias, Xp, 16384, 3072, K);
    hipMemsetAsync(hbuf, 0, 262144, stream);
    float* hO = hOutBase + (size_t)l * 32768;
    float* cO = cOutBase + (size_t)l * 32768;
    int* barL = bar + l * 512;   // flags[256] + epoch[1] per layer; fresh zeroed region
    void* args[] = { (void*)&Xp, (void*)&whh, (void*)&hbuf, (void*)&yBuf,
                     (void*)&hO, (void*)&cO, (void*)&barL };
    if (hipLaunchCooperativeKernel((void*)k_recurrent, dim3(256), dim3(128),
                                   args, 0, stream) != hipSuccess) {
      // fallback: plain launch (256 blocks, 50KB LDS, 128 thr -> all co-resident)
      k_recurrent<<<dim3(256), dim3(128), 0, stream>>>(Xp, whh, hbuf, yBuf,
                                                       hO, cO, barL);
    }
  }
}

// Round 5
// 19126.643 us; speedup vs baseline: 5.3974x; 1.2265x over previous
//
#include <hip/hip_runtime.h>

// DeepLSTM: B=32, S=512, IN=512, H=1024, 3H=3072, L=4
// out (fp32): cur [32][512][1024] | h_finals [4][32][1024] | c_finals [4][32][1024]
// ws (~192 MiB): Xp fp32 | hbuf (packed hi|lo words, TRANSPOSED [k][batch]) | bar
// Precision: split-bf16 (hi+lo) 3-term MFMA everywhere (~2^-16 rel); Xp fp32;
// inter-layer y fp32 staged in d_out's cur region; h carried as packed (hi,lo) bf16
// words; c in fp32 register.
// R1: distributed-flag barrier replaced 512-way same-line fetch_add.
// R2: master/broadcast barrier killed the poll storm (polls weren't dominant).
// R3: all mid-kernel coherence moved to agent-scope (sc1) relaxed atomics; deleted
//     per-step full-L2 wbl2/inv. 23.5 -> 15.9 us/step, variance gone.
// R4: kc stagger + unroll 16 eased LLC request serialization. 15.9 -> 10.7 us/step,
//     FETCH unchanged -> we are LLC request-RATE bound, not byte bound.
// R5: coalesce the h reads. Old layout [batch][k]: one wave load instruction touched
//     64 distinct lines at 8B/line (zero coalescing; 8192 line-req/wave/step; each
//     line fetched 8x). New layout hbuf[plane][k][batch]: a quad's 16 lanes read 16
//     consecutive words = one fully-used 64B line; 4 lines/instr; 1024 line-req/wave
//     /step (8x fewer). Loads become 8x u32 sc1 atomics per kc (identical unpack);
//     elementwise h-store transposes too (still line-coalesced per quad).

typedef unsigned short ushort_t;
typedef __attribute__((ext_vector_type(4))) float f32x4;
typedef __attribute__((ext_vector_type(8))) short s16x8;
typedef __attribute__((ext_vector_type(4))) short s16x4;

__device__ __forceinline__ unsigned short f2bf(float f) {
  union { float f; unsigned u; } v; v.f = f;
  unsigned r = (v.u + 0x7fffu + ((v.u >> 16) & 1u)) >> 16;
  return (unsigned short)r;
}
__device__ __forceinline__ float bf2f(unsigned short h) {
  union { unsigned u; float f; } v; v.u = ((unsigned)h) << 16; return v.f;
}
__device__ __forceinline__ void split2(float x, short& hi, short& lo) {
  unsigned short h = f2bf(x);
  hi = (short)h;
  lo = (short)f2bf(x - bf2f(h));
}

// ---------------- split-bf16 GEMM: C[m][n] = sum_k A[m][k]*Bw[n][k] + bias[n] ----------------
// A: fp32 [M][K]; Bw: fp32 [N][K]; C: fp32 [M][N]. BM=BN=128, BK=32. (unchanged)
#define BM 128
#define BN 128
#define BK 32
__global__ __launch_bounds__(256) void k_gemm_split(
    const float* __restrict__ A, const float* __restrict__ Bw,
    const float* __restrict__ bias, float* __restrict__ C,
    int M, int N, int K) {
  __shared__ short Ah[BM * BK], Al[BM * BK];
  __shared__ short Bh[BN * BK], Bl[BN * BK];
  const int tid = threadIdx.x;
  const int nbm = M / BM;
  const int bm = blockIdx.x % nbm;
  const int bn = blockIdx.x / nbm;
  const int lane = tid & 63;
  const int wave = tid >> 6;
  const int wm = (wave & 1) * 64;
  const int wn = (wave >> 1) * 64;
  const int q = lane >> 4;
  f32x4 acc[4][4] = {};
  const int nk = K / BK;
  for (int kt = 0; kt < nk; ++kt) {
    __syncthreads();
    const int kb = kt * BK;
#pragma unroll
    for (int i = 0; i < 4; ++i) {
      int idx = tid + i * 256;            // 0..1023
      int row = idx >> 3, c4 = (idx & 7) * 4;
      f32x4 ta = *(const f32x4*)(A + (size_t)(bm * BM + row) * K + kb + c4);
      s16x4 h4, l4;
#pragma unroll
      for (int j = 0; j < 4; ++j) { short hh, ll; split2(ta[j], hh, ll); h4[j] = hh; l4[j] = ll; }
      *(s16x4*)&Ah[row * BK + c4] = h4;
      *(s16x4*)&Al[row * BK + c4] = l4;
      f32x4 tb = *(const f32x4*)(Bw + (size_t)(bn * BN + row) * K + kb + c4);
#pragma unroll
      for (int j = 0; j < 4; ++j) { short hh, ll; split2(tb[j], hh, ll); h4[j] = hh; l4[j] = ll; }
      *(s16x4*)&Bh[row * BK + c4] = h4;
      *(s16x4*)&Bl[row * BK + c4] = l4;
    }
    __syncthreads();
    s16x8 ah[4], al[4], bh[4], bl[4];
#pragma unroll
    for (int i = 0; i < 4; ++i) {
      int r = (wm + i * 16 + (lane & 15)) * BK + q * 8;
      ah[i] = *(const s16x8*)&Ah[r];
      al[i] = *(const s16x8*)&Al[r];
      int rb = (wn + i * 16 + (lane & 15)) * BK + q * 8;
      bh[i] = *(const s16x8*)&Bh[rb];
      bl[i] = *(const s16x8*)&Bl[rb];
    }
#pragma unroll
    for (int mi = 0; mi < 4; ++mi)
#pragma unroll
      for (int ni = 0; ni < 4; ++ni) {
        acc[mi][ni] = __builtin_amdgcn_mfma_f32_16x16x32_bf16(ah[mi], bh[ni], acc[mi][ni], 0, 0, 0);
        acc[mi][ni] = __builtin_amdgcn_mfma_f32_16x16x32_bf16(al[mi], bh[ni], acc[mi][ni], 0, 0, 0);
        acc[mi][ni] = __builtin_amdgcn_mfma_f32_16x16x32_bf16(ah[mi], bl[ni], acc[mi][ni], 0, 0, 0);
      }
  }
#pragma unroll
  for (int mi = 0; mi < 4; ++mi)
#pragma unroll
    for (int ni = 0; ni < 4; ++ni) {
      int col = bn * BN + wn + ni * 16 + (lane & 15);
      float bv = bias[col];
#pragma unroll
      for (int r = 0; r < 4; ++r) {
        int row = bm * BM + wm + mi * 16 + q * 4 + r;
        C[(size_t)row * N + col] = acc[mi][ni][r] + bv;
      }
    }
}

// ---------------- persistent recurrent kernel (one layer, 512 steps) ----------------
// 256 blocks x 128 threads (2 waves). Wave g in {0,1}: batch group g*16..g*16+15.
// Block owns 4 hidden units u0..u0+3 (all 3 gates): s = (bid&7)*32 + (bid>>3) so
// consecutive unit-slices land on the same XCD (Xp/yOut 64B-line sharing in L2).
// LDS: split W_hh tile, 12 rows x K=1024, hi+lo = 48KB (shared by both waves) + red 2KB.
// hbuf: uint [2][1024 k][32 b] (TRANSPOSED), word = (bf16_hi<<16)|bf16_lo. All hbuf
// traffic is agent-scope relaxed atomic (sc1 -> LLC); reads are line-coalesced per
// 16-lane quad. NO cache maintenance in the loop.
// bar layout (per layer, 512 ints): [0..255] per-block step flags, [256] epoch word.
__global__ __launch_bounds__(128) void k_recurrent(
    const float* __restrict__ Xp,     // [16384][3072] fp32: x@Wih^T + b (rows m=b*512+t)
    const float* __restrict__ Whh,    // [3072][1024] fp32 (original weights)
    unsigned* __restrict__ hbuf,      // [2][1024][32] packed h words (pre-zeroed)
    float* __restrict__ yOut,         // [32][512][1024] fp32: layer output (cur region)
    float* __restrict__ hOut,         // [32][1024] f32
    float* __restrict__ cOut,         // [32][1024] f32
    int* __restrict__ bar)            // [512] ints: flags[256] + epoch, zeroed
{
  __shared__ short Wh[128 * 12 * 8];  // [kq][n][8] hi, 24 KB
  __shared__ short Wl[128 * 12 * 8];  // lo, 24 KB
  __shared__ float red[2][16][16];    // [g][batch][n], n: 0-3 i, 4-7 g, 8-11 o
  const int tid = threadIdx.x;
  const int lane = tid & 63;
  const int g = tid >> 6;             // wave = batch group
  const int bid = blockIdx.x;
  const int s = ((bid & 7) << 5) | (bid >> 3);  // XCD-grouped unit slice, bijective on [0,256)
  const int u0 = s * 4;
  const int b0 = g * 16;

  // stage + split W_hh rows for this slice (one-time, both waves cooperate)
  for (int p = tid; p < 1536; p += 128) {
    int n = p >> 7, kq = p & 127;
    int row = (n < 4) ? (u0 + n) : (n < 8) ? (1024 + u0 + (n - 4)) : (2048 + u0 + (n - 8));
    const float* src = Whh + (size_t)row * 1024 + kq * 8;
    f32x4 v0 = *(const f32x4*)src;
    f32x4 v1 = *(const f32x4*)(src + 4);
    s16x4 h4, l4;
#pragma unroll
    for (int j = 0; j < 4; ++j) { short hh, ll; split2(v0[j], hh, ll); h4[j] = hh; l4[j] = ll; }
    *(s16x4*)&Wh[(kq * 12 + n) * 8] = h4;
    *(s16x4*)&Wl[(kq * 12 + n) * 8] = l4;
#pragma unroll
    for (int j = 0; j < 4; ++j) { short hh, ll; split2(v1[j], hh, ll); h4[j] = hh; l4[j] = ll; }
    *(s16x4*)&Wh[(kq * 12 + n) * 8 + 4] = h4;
    *(s16x4*)&Wl[(kq * 12 + n) * 8 + 4] = l4;
  }

  const int m = lane & 15;            // batch-in-group (A row)
  const int q = lane >> 4;            // k quad
  const bool nvalid = m < 12;
  const int eb = (tid >> 2) & 15;     // elementwise batch-in-group
  const int eu = tid & 3;             // elementwise unit
  const int kc0 = s & 31;             // per-block kc stagger: spreads the 32 blocks of
                                      // each XCD across the 32 kc-stripes of the h-plane
  float c = 0.f;                      // cell state in register across all 512 steps
  __syncthreads();

  for (int t = 0; t < 512; ++t) {
    const int par = t & 1;
    // --- gate-input loads hoisted above matvec: latency hides under MFMA loop ---
    const size_t mrow = (size_t)(b0 + eb) * 512 + t;
    const float xi = Xp[mrow * 3072 + (u0 + eu)];
    const float xg = Xp[mrow * 3072 + 1024 + (u0 + eu)];
    const float xo = Xp[mrow * 3072 + 2048 + (u0 + eu)];

    // --- matvec: D[batch][n] = sum_k h[batch][k] * W[n][k], split-bf16 3-term ---
    // Transposed hbuf[par][k][b]: word addr = par*32768 + k*32 + batch. For one j,
    // each 16-lane quad (m=0..15, fixed q) reads 16 consecutive words = 1 full 64B
    // line -> 4 fully-used lines per instruction. sc1 (agent) loads: fresh from LLC.
    const unsigned* hp = hbuf + (size_t)par * 32768 + (b0 + m);
    f32x4 a0 = {0.f, 0.f, 0.f, 0.f}, a1 = a0, a2 = a0;
#pragma unroll 16
    for (int kci = 0; kci < 32; ++kci) {
      const int kc = (kci + kc0) & 31;
      const unsigned* p = hp + (kc * 32 + q * 8) * 32;  // + j*32 per word
      unsigned w0 = __hip_atomic_load(p + 0 * 32, __ATOMIC_RELAXED, __HIP_MEMORY_SCOPE_AGENT);
      unsigned w1 = __hip_atomic_load(p + 1 * 32, __ATOMIC_RELAXED, __HIP_MEMORY_SCOPE_AGENT);
      unsigned w2 = __hip_atomic_load(p + 2 * 32, __ATOMIC_RELAXED, __HIP_MEMORY_SCOPE_AGENT);
      unsigned w3 = __hip_atomic_load(p + 3 * 32, __ATOMIC_RELAXED, __HIP_MEMORY_SCOPE_AGENT);
      unsigned w4 = __hip_atomic_load(p + 4 * 32, __ATOMIC_RELAXED, __HIP_MEMORY_SCOPE_AGENT);
      unsigned w5 = __hip_atomic_load(p + 5 * 32, __ATOMIC_RELAXED, __HIP_MEMORY_SCOPE_AGENT);
      unsigned w6 = __hip_atomic_load(p + 6 * 32, __ATOMIC_RELAXED, __HIP_MEMORY_SCOPE_AGENT);
      unsigned w7 = __hip_atomic_load(p + 7 * 32, __ATOMIC_RELAXED, __HIP_MEMORY_SCOPE_AGENT);
      union { unsigned u[4]; s16x8 v; } H, L;
      H.u[0] = (w0 >> 16) | (w1 & 0xffff0000u); L.u[0] = (w0 & 0xffffu) | (w1 << 16);
      H.u[1] = (w2 >> 16) | (w3 & 0xffff0000u); L.u[1] = (w2 & 0xffffu) | (w3 << 16);
      H.u[2] = (w4 >> 16) | (w5 & 0xffff0000u); L.u[2] = (w4 & 0xffffu) | (w5 << 16);
      H.u[3] = (w6 >> 16) | (w7 & 0xffff0000u); L.u[3] = (w6 & 0xffffu) | (w7 << 16);
      s16x8 ahf = H.v, alf = L.v;
      s16x8 bhf = {}, blf = {};
      if (nvalid) {
        bhf = *(const s16x8*)&Wh[(((kc * 4 + q) * 12) + m) * 8];
        blf = *(const s16x8*)&Wl[(((kc * 4 + q) * 12) + m) * 8];
      }
      a0 = __builtin_amdgcn_mfma_f32_16x16x32_bf16(ahf, bhf, a0, 0, 0, 0);
      a1 = __builtin_amdgcn_mfma_f32_16x16x32_bf16(alf, bhf, a1, 0, 0, 0);
      a2 = __builtin_amdgcn_mfma_f32_16x16x32_bf16(ahf, blf, a2, 0, 0, 0);
    }
#pragma unroll
    for (int r = 0; r < 4; ++r)
      red[g][q * 4 + r][m] = a0[r] + a1[r] + a2[r];
    __syncthreads();

    // --- elementwise cell update: one thread per (g,b,u) ---
    {
      float ig = xi + red[g][eb][eu];
      float gg = xg + red[g][eb][4 + eu];
      float og = xo + red[g][eb][8 + eu];
      float si = 1.f / (1.f + expf(-ig));
      float tg = tanhf(gg);
      c += si * tg;
      float so = 1.f / (1.f + expf(-og));
      float h = so * tanhf(c);
      short hh, hl;
      split2(h, hh, hl);
      unsigned hword = ((unsigned)(unsigned short)hh << 16) | (unsigned)(unsigned short)hl;
      // transposed store: [unit][batch]; 16 lanes of a quad share a line
      size_t hw = (size_t)(1 - par) * 32768 + (size_t)(u0 + eu) * 32 + (b0 + eb);
      __hip_atomic_store(&hbuf[hw], hword, __ATOMIC_RELAXED, __HIP_MEMORY_SCOPE_AGENT);
      yOut[mrow * 1024 + (u0 + eu)] = h;
      if (t == 511) {
        hOut[(size_t)(b0 + eb) * 1024 + (u0 + eu)] = h;
        cOut[(size_t)(b0 + eb) * 1024 + (u0 + eu)] = c;
      }
    }
    if (t == 511) break;  // no successor step: kernel-end flush publishes outputs

    // ---- two-level grid barrier, zero cache-maintenance ----
    // Own wave's sc1 h-stores must be LLC-acked before the flag store (vmcnt is
    // per-wave; syncthreads covers the sibling wave). All barrier words are sc1,
    // so per-address LLC serialization gives transitive happens-before for h.
    const int tgt = t + 1;
    asm volatile("s_waitcnt vmcnt(0)" ::: "memory");
    __syncthreads();
    if (bid == 0) {
      if (tid == 0)
        __hip_atomic_store(&bar[0], tgt, __ATOMIC_RELAXED, __HIP_MEMORY_SCOPE_AGENT);
      for (;;) {
        int f0 = __hip_atomic_load(&bar[tid], __ATOMIC_RELAXED, __HIP_MEMORY_SCOPE_AGENT);
        int f1 = __hip_atomic_load(&bar[tid + 128], __ATOMIC_RELAXED, __HIP_MEMORY_SCOPE_AGENT);
        if (__syncthreads_and((f0 >= tgt) && (f1 >= tgt))) break;
        __builtin_amdgcn_s_sleep(1);
      }
      if (tid == 0)
        __hip_atomic_store(&bar[256], tgt, __ATOMIC_RELAXED, __HIP_MEMORY_SCOPE_AGENT);
    } else {
      if (tid == 0) {
        __hip_atomic_store(&bar[bid], tgt, __ATOMIC_RELAXED, __HIP_MEMORY_SCOPE_AGENT);
        while (__hip_atomic_load(&bar[256], __ATOMIC_RELAXED, __HIP_MEMORY_SCOPE_AGENT) < tgt)
          __builtin_amdgcn_s_sleep(1);
      }
      __syncthreads();
    }
    asm volatile("" ::: "memory");  // compiler barrier: no hoisting h loads above poll
  }
}

// ---------------- host ----------------
extern "C" void kernel_launch(void* const* d_in, const int* in_sizes, int n_in,
                              void* d_out, int out_size, void* d_ws, size_t ws_size,
                              hipStream_t stream) {
  const float* x     = (const float*)d_in[0];
  const float* w_ih0 = (const float*)d_in[1];
  const float* w_hh0 = (const float*)d_in[2];
  const float* b0v   = (const float*)d_in[3];
  const float* w_ihr = (const float*)d_in[4];
  const float* w_hhr = (const float*)d_in[5];
  const float* b_r   = (const float*)d_in[6];
  float* out = (float*)d_out;

  char* ws = (char*)d_ws;
  float*    Xp   = (float*)(ws);                   // 201,326,592 B
  unsigned* hbuf = (unsigned*)(ws + 201326592);    //     262,144 B (packed h words)
  int*      bar  = (int*)(ws + 201588736);         //       8,192 B (~192.3 MiB total)

  float* yBuf     = out;                 // cur region doubles as inter-layer y staging
  float* hOutBase = out + 16777216;
  float* cOutBase = out + 16777216 + 131072;

  hipMemsetAsync(bar, 0, 8192, stream);

  for (int l = 0; l < 4; ++l) {
    const float* wih  = (l == 0) ? w_ih0 : (w_ihr + (size_t)(l - 1) * 3072 * 1024);
    const float* whh  = (l == 0) ? w_hh0 : (w_hhr + (size_t)(l - 1) * 3072 * 1024);
    const float* bias = (l == 0) ? b0v : (b_r + (size_t)(l - 1) * 3072);
    const int K = (l == 0) ? 512 : 1024;
    const float* Ain = (l == 0) ? x : yBuf;
    dim3 ggrid((16384 / BM) * (3072 / BN));
    k_gemm_split<<<ggrid, 256, 0, stream>>>(Ain, wih, bias, Xp, 16384, 3072, K);
    hipMemsetAsync(hbuf, 0, 262144, stream);
    float* hO = hOutBase + (size_t)l * 32768;
    float* cO = cOutBase + (size_t)l * 32768;
    int* barL = bar + l * 512;   // flags[256] + epoch[1] per layer; fresh zeroed region
    void* args[] = { (void*)&Xp, (void*)&whh, (void*)&hbuf, (void*)&yBuf,
                     (void*)&hO, (void*)&cO, (void*)&barL };
    if (hipLaunchCooperativeKernel((void*)k_recurrent, dim3(256), dim3(128),
                                   args, 0, stream) != hipSuccess) {
      // fallback: plain launch (256 blocks, 50KB LDS, 128 thr -> all co-resident)
      k_recurrent<<<dim3(256), dim3(128), 0, stream>>>(Xp, whh, hbuf, yBuf,
                                                       hO, cO, barL);
    }
  }
}